// Round 9
// baseline (436.612 us; speedup 1.0000x reference)
//
#include <hip/hip_runtime.h>
#include <stdint.h>

#pragma clang fp contract(off)

#define Bn 2
#define Hn 512
#define Wn 512
#define Dn 128
#define HW (Hn * Wn)            // 262144
#define NRAY (Bn * HW)          // 524288
#define NSTEP 180
#define DTC 0.02f
#define D3 (Dn * Dn * Dn)

// ws layout: u32 [0..361] = 181 key pairs, [362] max bits, [363] min bits.
// byte 4096+: AoS float4 volume (Bn*D3 voxels, 67 MB) when ws_size permits.
#define WS_AOS_BYTE_OFF 4096
#define WS_AOS_BYTES ((size_t)Bn * D3 * 16)

typedef float f2 __attribute__((ext_vector_type(2)));

// exp fold: step = 0.02 * e^(0.01*sqrt2*px) = exp2(px*KEXP + LOG2DT)
#define KEXP  ((float)(0.01 * (double)1.41421354f * 1.4426950408889634))
#define LOG2DT (-5.643856189774724f)   // log2(0.02)

__device__ __forceinline__ uint32_t rotl32(uint32_t x, int n) {
    return (x << n) | (x >> (32 - n));
}

// JAX threefry2x32 (20 rounds, 5 groups of 4)
__device__ __forceinline__ void tf2x32(uint32_t k0, uint32_t k1,
                                       uint32_t& x0, uint32_t& x1) {
    uint32_t k2 = k0 ^ k1 ^ 0x1BD11BDAu;
    x0 += k0; x1 += k1;
    x0 += x1; x1 = rotl32(x1, 13); x1 ^= x0;
    x0 += x1; x1 = rotl32(x1, 15); x1 ^= x0;
    x0 += x1; x1 = rotl32(x1, 26); x1 ^= x0;
    x0 += x1; x1 = rotl32(x1, 6);  x1 ^= x0;
    x0 += k1; x1 += k2 + 1u;
    x0 += x1; x1 = rotl32(x1, 17); x1 ^= x0;
    x0 += x1; x1 = rotl32(x1, 29); x1 ^= x0;
    x0 += x1; x1 = rotl32(x1, 16); x1 ^= x0;
    x0 += x1; x1 = rotl32(x1, 24); x1 ^= x0;
    x0 += k2; x1 += k0 + 2u;
    x0 += x1; x1 = rotl32(x1, 13); x1 ^= x0;
    x0 += x1; x1 = rotl32(x1, 15); x1 ^= x0;
    x0 += x1; x1 = rotl32(x1, 26); x1 ^= x0;
    x0 += x1; x1 = rotl32(x1, 6);  x1 ^= x0;
    x0 += k0; x1 += k1 + 3u;
    x0 += x1; x1 = rotl32(x1, 17); x1 ^= x0;
    x0 += x1; x1 = rotl32(x1, 29); x1 ^= x0;
    x0 += x1; x1 = rotl32(x1, 16); x1 ^= x0;
    x0 += x1; x1 = rotl32(x1, 24); x1 ^= x0;
    x0 += k1; x1 += k2 + 4u;
    x0 += x1; x1 = rotl32(x1, 13); x1 ^= x0;
    x0 += x1; x1 = rotl32(x1, 15); x1 ^= x0;
    x0 += x1; x1 = rotl32(x1, 26); x1 ^= x0;
    x0 += x1; x1 = rotl32(x1, 6);  x1 ^= x0;
    x0 += k2; x1 += k0 + 5u;
}

// jax_threefry_partitionable random_bits: element i -> counter (0,i), o0^o1.
__device__ __forceinline__ uint32_t pbits(uint32_t k0, uint32_t k1, uint32_t i) {
    uint32_t x0 = 0u, x1 = i;
    tf2x32(k0, k1, x0, x1);
    return x0 ^ x1;
}

// Fast erfinv core: returns p*x (noise scale folded downstream).
__device__ __forceinline__ float erfinv_px(float x) {
    float a = fmaf(x, x, 0.0f);
    float w = -__logf(1.0f - a);
    float p;
    if (w < 5.0f) {
        w = w - 2.5f;
        p = 2.81022636e-08f;
        p = fmaf(p, w, 3.43273939e-07f);
        p = fmaf(p, w, -3.5233877e-06f);
        p = fmaf(p, w, -4.39150654e-06f);
        p = fmaf(p, w, 0.00021858087f);
        p = fmaf(p, w, -0.00125372503f);
        p = fmaf(p, w, -0.00417768164f);
        p = fmaf(p, w, 0.246640727f);
        p = fmaf(p, w, 1.50140941f);
    } else {
        w = sqrtf(w) - 3.0f;
        p = -0.000200214257f;
        p = fmaf(p, w, 0.000100950558f);
        p = fmaf(p, w, 0.00134934322f);
        p = fmaf(p, w, -0.00367342844f);
        p = fmaf(p, w, 0.00573950773f);
        p = fmaf(p, w, -0.0076224613f);
        p = fmaf(p, w, 0.00943887047f);
        p = fmaf(p, w, 1.00167406f);
        p = fmaf(p, w, 2.83297682f);
    }
    return p * x;
}

// packed lerp: d = a + w*(b-a)
__device__ __forceinline__ f2 plerp(f2 a, f2 b, f2 wv) {
    return __builtin_elementwise_fma(wv, b - a, a);
}

__global__ void init_keys_kernel(uint32_t* __restrict__ ws) {
    int t = threadIdx.x;
    if (t <= 180) {
        uint32_t x0 = 0u, x1 = (uint32_t)t;
        tf2x32(0u, 42u, x0, x1);
        ws[2 * t]     = x0;
        ws[2 * t + 1] = x1;
    }
    if (t == 181) ws[362] = 0u;
    if (t == 182) ws[363] = 0x7f7fffffu;
}

// SoA (b,c,z,y,x) -> AoS float4 per voxel; block 0 also derives RNG keys.
__global__ __launch_bounds__(256) void repack_kernel(
    const float* __restrict__ tpl, float4* __restrict__ aos,
    uint32_t* __restrict__ ws) {
    if (blockIdx.x == 0) {
        int t = threadIdx.x;
        if (t <= 180) {
            uint32_t x0 = 0u, x1 = (uint32_t)t;
            tf2x32(0u, 42u, x0, x1);         // fold_in(key(42), t)
            ws[2 * t]     = x0;
            ws[2 * t + 1] = x1;
        }
        if (t == 181) ws[362] = 0u;              // running max (len >= 0)
        if (t == 182) ws[363] = 0x7f7fffffu;     // running min = FLT_MAX bits
    }
    int i = blockIdx.x * 256 + threadIdx.x;
    if (i >= Bn * D3) return;
    int b = i >> 21;                 // / D3 (D3 = 2^21)
    int v = i & (D3 - 1);
    const float* base = tpl + (size_t)b * 4 * D3 + v;
    float4 o;
    o.x = base[0];
    o.y = base[D3];
    o.z = base[2 * D3];
    o.w = base[3 * D3];
    aos[i] = o;
}

template <bool PACKED>
__global__ __launch_bounds__(256) void march_kernel(
    const float* __restrict__ rot, const float* __restrict__ cpos,
    const float* __restrict__ focal, const float* __restrict__ pp,
    const float* __restrict__ pix, const float* __restrict__ tpl,
    const float4* __restrict__ aos,
    const float* __restrict__ bg, float* __restrict__ out,
    uint32_t* __restrict__ ws)
{
    #pragma clang fp contract(off)
    __shared__ uint2 skeys[181];
    for (int i = threadIdx.x; i < 181; i += 256) {
        skeys[i] = make_uint2(ws[2 * i], ws[2 * i + 1]);
    }
    __syncthreads();

    const int idx = blockIdx.x * 256 + threadIdx.x;
    const int b = idx >> 18;          // / HW
    const int p = idx & (HW - 1);

    // ---- ray setup (trajectory-critical: separate roundings preserved) ----
    float px = pix[(size_t)idx * 2 + 0];
    float py = pix[(size_t)idx * 2 + 1];
    float v0 = (px - pp[b * 2 + 0]) / focal[b * 2 + 0];
    float v1 = (py - pp[b * 2 + 1]) / focal[b * 2 + 1];
    const float* R = rot + b * 9;
    float rdx = (R[0] * v0 + R[3] * v1) + R[6];
    float rdy = (R[1] * v0 + R[4] * v1) + R[7];
    float rdz = (R[2] * v0 + R[5] * v1) + R[8];
    float nrm = sqrtf((rdx * rdx + rdy * rdy) + rdz * rdz);
    rdx = rdx / nrm; rdy = rdy / nrm; rdz = rdz / nrm;
    float cpx = cpos[b * 3 + 0], cpy = cpos[b * 3 + 1], cpz = cpos[b * 3 + 2];

    float t1x = (-1.0f - cpx) / rdx, t2x = (1.0f - cpx) / rdx;
    float t1y = (-1.0f - cpy) / rdy, t2y = (1.0f - cpy) / rdy;
    float t1z = (-1.0f - cpz) / rdz, t2z = (1.0f - cpz) / rdz;
    float tmin = fmaxf(fminf(t1x, t2x), fmaxf(fminf(t1y, t2y), fminf(t1z, t2z)));
    float tmax = fminf(fmaxf(t1x, t2x), fminf(fmaxf(t1y, t2y), fmaxf(t1z, t2z)));
    bool hit = tmin < tmax;
    float t = fmaxf(hit ? tmin : 0.0f, 0.0f);

    // initial jitter: uniform [0,1) under fold_in(key,0), partitionable bits
    {
        uint2 k0 = skeys[0];
        uint32_t bits = pbits(k0.x, k0.y, (uint32_t)idx);
        float u = __uint_as_float((bits >> 9) | 0x3f800000u) - 1.0f;
        u = fmaxf(0.0f, u);
        t = t - DTC * u;
    }

    float posx = cpx + rdx * t;
    float posy = cpy + rdy * t;
    float posz = cpz + rdz * t;

    float alpha = 0.0f, len = 0.0f;
    f2 acc_rg = {0.0f, 0.0f};
    float acc_b = 0.0f;
    const float* vol = tpl + (size_t)b * 4 * D3;
    const char* vbase = (const char*)(aos + (size_t)b * D3);
    const float LO = -0.99999994f;  // nextafter(-1, 0) in f32

    for (int i = 0; i < NSTEP; ++i) {
        // per-step normal noise under fold_in(key, i+1), partitionable bits
        uint2 kk = skeys[i + 1];
        uint32_t bits = pbits(kk.x, kk.y, (uint32_t)idx);
        float f = __uint_as_float((bits >> 9) | 0x3f800000u) - 1.0f;
        float uu = fmaxf(LO, fmaf(f, 2.0f, LO));
        float pw = erfinv_px(uu);
        // step = 0.02 * exp(0.01*sqrt2*pw), folded into one exp2
        float step = exp2f(fmaf(pw, KEXP, LOG2DT));

        // valid = max(|x|,|y|,|z|) < 1  (v_max3 with abs modifiers)
        float m = fmaxf(fmaxf(fabsf(posx), fabsf(posy)), fabsf(posz));
        bool valid = m < 1.0f;

        float contrib = 0.0f;
        if (valid && (alpha < 1.0f)) {
            // g = (pos+1)*0.5*127 == fma(pos, 63.5, 63.5); trilinear is
            // continuous across floor boundaries so ulp diffs are harmless.
            float gx = fmaf(posx, 63.5f, 63.5f);
            float gy = fmaf(posy, 63.5f, 63.5f);
            float gz = fmaf(posz, 63.5f, 63.5f);
            float fx = floorf(gx), fy = floorf(gy), fz = floorf(gz);
            float wx = gx - fx, wy = gy - fy, wz = gz - fz;
            int ix0 = (int)fx, iy0 = (int)fy, iz0 = (int)fz;

            float sx, sy, sz, sw;
            if (PACKED) {
                // byte offsets, pre-shifted (float4=16B; row 2^11 B; slab 2^18 B)
                uint32_t xb  = (uint32_t)min(ix0, Dn - 2) << 4;
                float wxe = (ix0 < Dn - 1) ? wx : 1.0f;
                uint32_t yb0 = (uint32_t)iy0 << 11;
                uint32_t yb1 = min(yb0 + (1u << 11), (uint32_t)(Dn - 1) << 11);
                uint32_t zb0 = (uint32_t)iz0 << 18;
                uint32_t zb1 = min(zb0 + (1u << 18), (uint32_t)(Dn - 1) << 18);

                uint32_t o00 = zb0 + yb0 + xb;
                uint32_t o01 = zb0 + yb1 + xb;
                uint32_t o10 = zb1 + yb0 + xb;
                uint32_t o11 = zb1 + yb1 + xb;

                float4 A00 = *(const float4*)(vbase + o00);
                float4 B00 = *(const float4*)(vbase + o00 + 16);
                float4 A01 = *(const float4*)(vbase + o01);
                float4 B01 = *(const float4*)(vbase + o01 + 16);
                float4 A10 = *(const float4*)(vbase + o10);
                float4 B10 = *(const float4*)(vbase + o10 + 16);
                float4 A11 = *(const float4*)(vbase + o11);
                float4 B11 = *(const float4*)(vbase + o11 + 16);

                f2 wxv = {wxe, wxe}, wyv = {wy, wy}, wzv = {wz, wz};
                f2 c00rg = plerp((f2){A00.x, A00.y}, (f2){B00.x, B00.y}, wxv);
                f2 c00ba = plerp((f2){A00.z, A00.w}, (f2){B00.z, B00.w}, wxv);
                f2 c01rg = plerp((f2){A01.x, A01.y}, (f2){B01.x, B01.y}, wxv);
                f2 c01ba = plerp((f2){A01.z, A01.w}, (f2){B01.z, B01.w}, wxv);
                f2 c10rg = plerp((f2){A10.x, A10.y}, (f2){B10.x, B10.y}, wxv);
                f2 c10ba = plerp((f2){A10.z, A10.w}, (f2){B10.z, B10.w}, wxv);
                f2 c11rg = plerp((f2){A11.x, A11.y}, (f2){B11.x, B11.y}, wxv);
                f2 c11ba = plerp((f2){A11.z, A11.w}, (f2){B11.z, B11.w}, wxv);
                f2 c0rg = plerp(c00rg, c01rg, wyv);
                f2 c0ba = plerp(c00ba, c01ba, wyv);
                f2 c1rg = plerp(c10rg, c11rg, wyv);
                f2 c1ba = plerp(c10ba, c11ba, wyv);
                f2 srg = plerp(c0rg, c1rg, wzv);
                f2 sba = plerp(c0ba, c1ba, wzv);
                sx = srg.x; sy = srg.y; sz = sba.x; sw = sba.y;
            } else {
                int ix1 = min(ix0 + 1, Dn - 1);
                int iy1 = min(iy0 + 1, Dn - 1);
                int iz1 = min(iz0 + 1, Dn - 1);
                float owx = 1.0f - wx, owy = 1.0f - wy, owz = 1.0f - wz;
                size_t o00 = ((size_t)iz0 * Dn + iy0) * Dn;
                size_t o01 = ((size_t)iz0 * Dn + iy1) * Dn;
                size_t o10 = ((size_t)iz1 * Dn + iy0) * Dn;
                size_t o11 = ((size_t)iz1 * Dn + iy1) * Dn;
                float s[4];
                #pragma unroll
                for (int c = 0; c < 4; ++c) {
                    const float* vc = vol + (size_t)c * D3;
                    float c00 = vc[o00 + ix0] * owx + vc[o00 + ix1] * wx;
                    float c01 = vc[o01 + ix0] * owx + vc[o01 + ix1] * wx;
                    float c10 = vc[o10 + ix0] * owx + vc[o10 + ix1] * wx;
                    float c11 = vc[o11 + ix0] * owx + vc[o11 + ix1] * wx;
                    float cc0 = c00 * owy + c01 * wy;
                    float cc1 = c10 * owy + c11 * wy;
                    s[c] = cc0 * owz + cc1 * wz;
                }
                sx = s[0]; sy = s[1]; sz = s[2]; sw = s[3];
            }
            contrib = fminf(fmaf(sw, step, alpha), 1.0f) - alpha;
            f2 cv = {contrib, contrib};
            acc_rg = __builtin_elementwise_fma((f2){sx, sy}, cv, acc_rg);
            acc_b = fmaf(sz, contrib, acc_b);
        }
        alpha = alpha + contrib;
        if (contrib == 0.0f) len = len + step;
        posx = fmaf(rdx, step, posx);
        posy = fmaf(rdy, step, posy);
        posz = fmaf(rdz, step, posz);
    }

    // ---- epilogue: rgb + background blend, alpha, raw length ----
    size_t obase = (size_t)b * 3 * HW + p;
    out[obase]            = acc_rg.x + (1.0f - alpha) * fmaxf(bg[obase], 0.0f);
    out[obase + HW]       = acc_rg.y + (1.0f - alpha) * fmaxf(bg[obase + HW], 0.0f);
    out[obase + 2 * HW]   = acc_b   + (1.0f - alpha) * fmaxf(bg[obase + 2 * HW], 0.0f);
    out[(size_t)Bn * 3 * HW + (size_t)b * HW + p] = alpha;
    out[(size_t)Bn * 4 * HW + (size_t)b * HW + p] = len;

    // ---- block reduce min/max of len (len >= 0: uint order == float order) ----
    __shared__ float smax[256];
    __shared__ float smin[256];
    smax[threadIdx.x] = len;
    smin[threadIdx.x] = len;
    __syncthreads();
    for (int s = 128; s > 0; s >>= 1) {
        if (threadIdx.x < s) {
            smax[threadIdx.x] = fmaxf(smax[threadIdx.x], smax[threadIdx.x + s]);
            smin[threadIdx.x] = fminf(smin[threadIdx.x], smin[threadIdx.x + s]);
        }
        __syncthreads();
    }
    if (threadIdx.x == 0) {
        atomicMax((unsigned int*)&ws[362], __float_as_uint(smax[0]));
        atomicMin((unsigned int*)&ws[363], __float_as_uint(smin[0]));
    }
}

__global__ void finalize_kernel(float* __restrict__ out,
                                const uint32_t* __restrict__ ws) {
    #pragma clang fp contract(off)
    int i = blockIdx.x * blockDim.x + threadIdx.x;
    if (i >= NRAY) return;
    float mx = __uint_as_float(ws[362]);
    float mn = __uint_as_float(ws[363]);
    float a = out[(size_t)Bn * 3 * HW + i];
    size_t loff = (size_t)Bn * 4 * HW + i;
    float l = out[loff];
    out[loff] = (a * l) / (mx + mn);
}

extern "C" void kernel_launch(void* const* d_in, const int* in_sizes, int n_in,
                              void* d_out, int out_size, void* d_ws, size_t ws_size,
                              hipStream_t stream) {
    const float* rot   = (const float*)d_in[0];
    const float* cpos  = (const float*)d_in[1];
    const float* focal = (const float*)d_in[2];
    const float* pp    = (const float*)d_in[3];
    const float* pix   = (const float*)d_in[4];
    const float* tpl   = (const float*)d_in[5];
    const float* bg    = (const float*)d_in[6];
    float* out = (float*)d_out;
    uint32_t* ws = (uint32_t*)d_ws;
    float4* aos = (float4*)((char*)d_ws + WS_AOS_BYTE_OFF);

    const bool packed = ws_size >= WS_AOS_BYTE_OFF + WS_AOS_BYTES;

    if (packed) {
        hipLaunchKernelGGL(repack_kernel, dim3((Bn * D3) / 256), dim3(256), 0,
                           stream, tpl, aos, ws);
        hipLaunchKernelGGL(march_kernel<true>, dim3(NRAY / 256), dim3(256), 0,
                           stream, rot, cpos, focal, pp, pix, tpl, aos, bg, out, ws);
    } else {
        hipLaunchKernelGGL(init_keys_kernel, dim3(1), dim3(256), 0, stream, ws);
        hipLaunchKernelGGL(march_kernel<false>, dim3(NRAY / 256), dim3(256), 0,
                           stream, rot, cpos, focal, pp, pix, tpl, aos, bg, out, ws);
    }
    hipLaunchKernelGGL(finalize_kernel, dim3(NRAY / 256), dim3(256), 0, stream,
                       out, ws);
}

// Round 10
// 435.182 us; speedup vs baseline: 1.0033x; 1.0033x over previous
//
#include <hip/hip_runtime.h>
#include <stdint.h>

#pragma clang fp contract(off)

#define Bn 2
#define Hn 512
#define Wn 512
#define Dn 128
#define HW (Hn * Wn)            // 262144
#define NRAY (Bn * HW)          // 524288
#define NSTEP 180
#define DTC 0.02f
#define D3 (Dn * Dn * Dn)

// ws layout: u32 [0..361] = 181 key pairs, [362] max bits, [363] min bits.
// byte 4096+: AoS float4 volume (Bn*D3 voxels, 67 MB) when ws_size permits.
#define WS_AOS_BYTE_OFF 4096
#define WS_AOS_BYTES ((size_t)Bn * D3 * 16)

typedef float f2 __attribute__((ext_vector_type(2)));

// step = 0.02 * e^(0.01*sqrt2*pw) = exp2(pw*KEXP + LOG2DT)
#define KEXP  ((float)(0.01 * (double)1.41421354f * 1.4426950408889634))
#define LOG2DT (-5.643856189774724f)   // log2(0.02)

__device__ __forceinline__ uint32_t rotl32(uint32_t x, int n) {
    return (x << n) | (x >> (32 - n));
}

// JAX threefry2x32 (20 rounds, 5 groups of 4)
__device__ __forceinline__ void tf2x32(uint32_t k0, uint32_t k1,
                                       uint32_t& x0, uint32_t& x1) {
    uint32_t k2 = k0 ^ k1 ^ 0x1BD11BDAu;
    x0 += k0; x1 += k1;
    x0 += x1; x1 = rotl32(x1, 13); x1 ^= x0;
    x0 += x1; x1 = rotl32(x1, 15); x1 ^= x0;
    x0 += x1; x1 = rotl32(x1, 26); x1 ^= x0;
    x0 += x1; x1 = rotl32(x1, 6);  x1 ^= x0;
    x0 += k1; x1 += k2 + 1u;
    x0 += x1; x1 = rotl32(x1, 17); x1 ^= x0;
    x0 += x1; x1 = rotl32(x1, 29); x1 ^= x0;
    x0 += x1; x1 = rotl32(x1, 16); x1 ^= x0;
    x0 += x1; x1 = rotl32(x1, 24); x1 ^= x0;
    x0 += k2; x1 += k0 + 2u;
    x0 += x1; x1 = rotl32(x1, 13); x1 ^= x0;
    x0 += x1; x1 = rotl32(x1, 15); x1 ^= x0;
    x0 += x1; x1 = rotl32(x1, 26); x1 ^= x0;
    x0 += x1; x1 = rotl32(x1, 6);  x1 ^= x0;
    x0 += k0; x1 += k1 + 3u;
    x0 += x1; x1 = rotl32(x1, 17); x1 ^= x0;
    x0 += x1; x1 = rotl32(x1, 29); x1 ^= x0;
    x0 += x1; x1 = rotl32(x1, 16); x1 ^= x0;
    x0 += x1; x1 = rotl32(x1, 24); x1 ^= x0;
    x0 += k1; x1 += k2 + 4u;
    x0 += x1; x1 = rotl32(x1, 13); x1 ^= x0;
    x0 += x1; x1 = rotl32(x1, 15); x1 ^= x0;
    x0 += x1; x1 = rotl32(x1, 26); x1 ^= x0;
    x0 += x1; x1 = rotl32(x1, 6);  x1 ^= x0;
    x0 += k2; x1 += k0 + 5u;
}

// jax_threefry_partitionable random_bits: element i -> counter (0,i), o0^o1.
__device__ __forceinline__ uint32_t pbits(uint32_t k0, uint32_t k1, uint32_t i) {
    uint32_t x0 = 0u, x1 = i;
    tf2x32(k0, k1, x0, x1);
    return x0 ^ x1;
}

// Fast erfinv core: returns p*x.
__device__ __forceinline__ float erfinv_px(float x) {
    float a = x * x;
    float w = -__logf(1.0f - a);
    float p;
    if (w < 5.0f) {
        w = w - 2.5f;
        p = 2.81022636e-08f;
        p = fmaf(p, w, 3.43273939e-07f);
        p = fmaf(p, w, -3.5233877e-06f);
        p = fmaf(p, w, -4.39150654e-06f);
        p = fmaf(p, w, 0.00021858087f);
        p = fmaf(p, w, -0.00125372503f);
        p = fmaf(p, w, -0.00417768164f);
        p = fmaf(p, w, 0.246640727f);
        p = fmaf(p, w, 1.50140941f);
    } else {
        w = sqrtf(w) - 3.0f;
        p = -0.000200214257f;
        p = fmaf(p, w, 0.000100950558f);
        p = fmaf(p, w, 0.00134934322f);
        p = fmaf(p, w, -0.00367342844f);
        p = fmaf(p, w, 0.00573950773f);
        p = fmaf(p, w, -0.0076224613f);
        p = fmaf(p, w, 0.00943887047f);
        p = fmaf(p, w, 1.00167406f);
        p = fmaf(p, w, 2.83297682f);
    }
    return p * x;
}

// noise->step, all native ops: uf in [1,2) -> uu -> erfinv -> exp2
__device__ __forceinline__ float step_from_bits(uint32_t bits) {
    float uf = __uint_as_float((bits >> 9) | 0x3f800000u);
    float uu = fmaxf(-0.99999994f, fmaf(uf, 2.0f, -3.0f));
    float pw = erfinv_px(uu);
    return __builtin_amdgcn_exp2f(fmaf(pw, KEXP, LOG2DT));
}

// packed lerp: d = a + w*(b-a)
__device__ __forceinline__ f2 plerp(f2 a, f2 b, f2 wv) {
    return __builtin_elementwise_fma(wv, b - a, a);
}

__global__ void init_keys_kernel(uint32_t* __restrict__ ws) {
    int t = threadIdx.x;
    if (t <= 180) {
        uint32_t x0 = 0u, x1 = (uint32_t)t;
        tf2x32(0u, 42u, x0, x1);
        ws[2 * t]     = x0;
        ws[2 * t + 1] = x1;
    }
    if (t == 181) ws[362] = 0u;
    if (t == 182) ws[363] = 0x7f7fffffu;
}

// SoA (b,c,z,y,x) -> AoS float4 per voxel; block 0 also derives RNG keys.
__global__ __launch_bounds__(256) void repack_kernel(
    const float* __restrict__ tpl, float4* __restrict__ aos,
    uint32_t* __restrict__ ws) {
    if (blockIdx.x == 0) {
        int t = threadIdx.x;
        if (t <= 180) {
            uint32_t x0 = 0u, x1 = (uint32_t)t;
            tf2x32(0u, 42u, x0, x1);         // fold_in(key(42), t)
            ws[2 * t]     = x0;
            ws[2 * t + 1] = x1;
        }
        if (t == 181) ws[362] = 0u;              // running max (len >= 0)
        if (t == 182) ws[363] = 0x7f7fffffu;     // running min = FLT_MAX bits
    }
    int i = blockIdx.x * 256 + threadIdx.x;
    if (i >= Bn * D3) return;
    int b = i >> 21;                 // / D3 (D3 = 2^21)
    int v = i & (D3 - 1);
    const float* base = tpl + (size_t)b * 4 * D3 + v;
    float4 o;
    o.x = base[0];
    o.y = base[D3];
    o.z = base[2 * D3];
    o.w = base[3 * D3];
    aos[i] = o;
}

template <bool PACKED>
__global__ __launch_bounds__(256) void march_kernel(
    const float* __restrict__ rot, const float* __restrict__ cpos,
    const float* __restrict__ focal, const float* __restrict__ pp,
    const float* __restrict__ pix, const float* __restrict__ tpl,
    const float4* __restrict__ aos,
    const float* __restrict__ bg, float* __restrict__ out,
    uint32_t* __restrict__ ws)
{
    #pragma clang fp contract(off)
    __shared__ uint2 skeys[181];
    for (int i = threadIdx.x; i < 181; i += 256) {
        skeys[i] = make_uint2(ws[2 * i], ws[2 * i + 1]);
    }
    __syncthreads();

    const int idx = blockIdx.x * 256 + threadIdx.x;
    const int b = idx >> 18;          // / HW
    const int p = idx & (HW - 1);

    // ---- ray setup (trajectory-critical: separate roundings preserved) ----
    float px = pix[(size_t)idx * 2 + 0];
    float py = pix[(size_t)idx * 2 + 1];
    float v0 = (px - pp[b * 2 + 0]) / focal[b * 2 + 0];
    float v1 = (py - pp[b * 2 + 1]) / focal[b * 2 + 1];
    const float* R = rot + b * 9;
    float rdx = (R[0] * v0 + R[3] * v1) + R[6];
    float rdy = (R[1] * v0 + R[4] * v1) + R[7];
    float rdz = (R[2] * v0 + R[5] * v1) + R[8];
    float nrm = sqrtf((rdx * rdx + rdy * rdy) + rdz * rdz);
    rdx = rdx / nrm; rdy = rdy / nrm; rdz = rdz / nrm;
    float cpx = cpos[b * 3 + 0], cpy = cpos[b * 3 + 1], cpz = cpos[b * 3 + 2];

    float t1x = (-1.0f - cpx) / rdx, t2x = (1.0f - cpx) / rdx;
    float t1y = (-1.0f - cpy) / rdy, t2y = (1.0f - cpy) / rdy;
    float t1z = (-1.0f - cpz) / rdz, t2z = (1.0f - cpz) / rdz;
    float tmin = fmaxf(fminf(t1x, t2x), fmaxf(fminf(t1y, t2y), fminf(t1z, t2z)));
    float tmax = fminf(fmaxf(t1x, t2x), fminf(fmaxf(t1y, t2y), fmaxf(t1z, t2z)));
    bool hit = tmin < tmax;
    float t = fmaxf(hit ? tmin : 0.0f, 0.0f);

    // initial jitter: uniform [0,1) under fold_in(key,0), partitionable bits
    {
        uint2 k0 = skeys[0];
        uint32_t bits = pbits(k0.x, k0.y, (uint32_t)idx);
        float u = __uint_as_float((bits >> 9) | 0x3f800000u) - 1.0f;
        u = fmaxf(0.0f, u);
        t = t - DTC * u;
    }

    float posx = cpx + rdx * t;
    float posy = cpy + rdy * t;
    float posz = cpz + rdz * t;

    float alpha = 0.0f, len = 0.0f;
    f2 acc_rg = {0.0f, 0.0f};
    float acc_b = 0.0f;
    const float* vol = tpl + (size_t)b * 4 * D3;
    const char* vbase = (const char*)(aos + (size_t)b * D3);
    bool entered = false;

    int i = 0;
    for (; i < NSTEP; ++i) {
        // per-step normal noise under fold_in(key, i+1), partitionable bits
        uint2 kk = skeys[i + 1];
        float step = step_from_bits(pbits(kk.x, kk.y, (uint32_t)idx));

        // valid = max(|x|,|y|,|z|) < 1; sampling adds alpha < 1 in one cmp
        float m = fmaxf(fmaxf(fabsf(posx), fabsf(posy)), fabsf(posz));
        bool valid = m < 1.0f;
        bool sampling = fmaxf(m, alpha) < 1.0f;

        float contrib = 0.0f;
        if (sampling) {
            // pos in (-1,1) strictly => g in [0,127], no clamps needed
            float gx = fmaf(posx, 63.5f, 63.5f);
            float gy = fmaf(posy, 63.5f, 63.5f);
            float gz = fmaf(posz, 63.5f, 63.5f);
            float fx = floorf(gx), fy = floorf(gy), fz = floorf(gz);
            float wx = gx - fx, wy = gy - fy, wz = gz - fz;
            int ix0 = (int)fx, iy0 = (int)fy, iz0 = (int)fz;

            float sx, sy, sz, sw;
            if (PACKED) {
                uint32_t xb  = (uint32_t)min(ix0, Dn - 2) << 4;
                float wxe = (ix0 < Dn - 1) ? wx : 1.0f;
                uint32_t yb0 = (uint32_t)iy0 << 11;
                uint32_t yb1 = min(yb0 + (1u << 11), (uint32_t)(Dn - 1) << 11);
                uint32_t zb0 = (uint32_t)iz0 << 18;
                uint32_t zb1 = min(zb0 + (1u << 18), (uint32_t)(Dn - 1) << 18);

                uint32_t o00 = zb0 + yb0 + xb;
                uint32_t o01 = zb0 + yb1 + xb;
                uint32_t o10 = zb1 + yb0 + xb;
                uint32_t o11 = zb1 + yb1 + xb;

                float4 A00 = *(const float4*)(vbase + o00);
                float4 B00 = *(const float4*)(vbase + o00 + 16);
                float4 A01 = *(const float4*)(vbase + o01);
                float4 B01 = *(const float4*)(vbase + o01 + 16);
                float4 A10 = *(const float4*)(vbase + o10);
                float4 B10 = *(const float4*)(vbase + o10 + 16);
                float4 A11 = *(const float4*)(vbase + o11);
                float4 B11 = *(const float4*)(vbase + o11 + 16);

                f2 wxv = {wxe, wxe}, wyv = {wy, wy}, wzv = {wz, wz};
                f2 c00rg = plerp((f2){A00.x, A00.y}, (f2){B00.x, B00.y}, wxv);
                f2 c00ba = plerp((f2){A00.z, A00.w}, (f2){B00.z, B00.w}, wxv);
                f2 c01rg = plerp((f2){A01.x, A01.y}, (f2){B01.x, B01.y}, wxv);
                f2 c01ba = plerp((f2){A01.z, A01.w}, (f2){B01.z, B01.w}, wxv);
                f2 c10rg = plerp((f2){A10.x, A10.y}, (f2){B10.x, B10.y}, wxv);
                f2 c10ba = plerp((f2){A10.z, A10.w}, (f2){B10.z, B10.w}, wxv);
                f2 c11rg = plerp((f2){A11.x, A11.y}, (f2){B11.x, B11.y}, wxv);
                f2 c11ba = plerp((f2){A11.z, A11.w}, (f2){B11.z, B11.w}, wxv);
                f2 c0rg = plerp(c00rg, c01rg, wyv);
                f2 c0ba = plerp(c00ba, c01ba, wyv);
                f2 c1rg = plerp(c10rg, c11rg, wyv);
                f2 c1ba = plerp(c10ba, c11ba, wyv);
                f2 srg = plerp(c0rg, c1rg, wzv);
                f2 sba = plerp(c0ba, c1ba, wzv);
                sx = srg.x; sy = srg.y; sz = sba.x; sw = sba.y;
            } else {
                int ix1 = min(ix0 + 1, Dn - 1);
                int iy1 = min(iy0 + 1, Dn - 1);
                int iz1 = min(iz0 + 1, Dn - 1);
                float owx = 1.0f - wx, owy = 1.0f - wy, owz = 1.0f - wz;
                size_t o00 = ((size_t)iz0 * Dn + iy0) * Dn;
                size_t o01 = ((size_t)iz0 * Dn + iy1) * Dn;
                size_t o10 = ((size_t)iz1 * Dn + iy0) * Dn;
                size_t o11 = ((size_t)iz1 * Dn + iy1) * Dn;
                float s[4];
                #pragma unroll
                for (int c = 0; c < 4; ++c) {
                    const float* vc = vol + (size_t)c * D3;
                    float c00 = vc[o00 + ix0] * owx + vc[o00 + ix1] * wx;
                    float c01 = vc[o01 + ix0] * owx + vc[o01 + ix1] * wx;
                    float c10 = vc[o10 + ix0] * owx + vc[o10 + ix1] * wx;
                    float c11 = vc[o11 + ix0] * owx + vc[o11 + ix1] * wx;
                    float cc0 = c00 * owy + c01 * wy;
                    float cc1 = c10 * owy + c11 * wy;
                    s[c] = cc0 * owz + cc1 * wz;
                }
                sx = s[0]; sy = s[1]; sz = s[2]; sw = s[3];
            }
            contrib = fminf(fmaf(sw, step, alpha), 1.0f) - alpha;
            f2 cv = {contrib, contrib};
            acc_rg = __builtin_elementwise_fma((f2){sx, sy}, cv, acc_rg);
            acc_b = fmaf(sz, contrib, acc_b);
        }
        alpha = alpha + contrib;
        if (contrib == 0.0f) len = len + step;
        posx = fmaf(rdx, step, posx);
        posy = fmaf(rdy, step, posy);
        posz = fmaf(rdz, step, posz);

        // permanently done: saturated, or entered-the-box-then-exited
        // (straight line through a convex box => valid-set is one interval)
        bool done = (alpha >= 1.0f) || (entered && !valid);
        entered = entered || valid;
        if (__all(done)) { ++i; break; }
    }
    // tail: every remaining step has contrib == 0 -> only len accumulates
    for (; i < NSTEP; ++i) {
        uint2 kk = skeys[i + 1];
        len = len + step_from_bits(pbits(kk.x, kk.y, (uint32_t)idx));
    }

    // ---- epilogue: rgb + background blend, alpha, raw length ----
    size_t obase = (size_t)b * 3 * HW + p;
    out[obase]            = acc_rg.x + (1.0f - alpha) * fmaxf(bg[obase], 0.0f);
    out[obase + HW]       = acc_rg.y + (1.0f - alpha) * fmaxf(bg[obase + HW], 0.0f);
    out[obase + 2 * HW]   = acc_b   + (1.0f - alpha) * fmaxf(bg[obase + 2 * HW], 0.0f);
    out[(size_t)Bn * 3 * HW + (size_t)b * HW + p] = alpha;
    out[(size_t)Bn * 4 * HW + (size_t)b * HW + p] = len;

    // ---- block reduce min/max of len (len >= 0: uint order == float order) ----
    __shared__ float smax[256];
    __shared__ float smin[256];
    smax[threadIdx.x] = len;
    smin[threadIdx.x] = len;
    __syncthreads();
    for (int s = 128; s > 0; s >>= 1) {
        if (threadIdx.x < s) {
            smax[threadIdx.x] = fmaxf(smax[threadIdx.x], smax[threadIdx.x + s]);
            smin[threadIdx.x] = fminf(smin[threadIdx.x], smin[threadIdx.x + s]);
        }
        __syncthreads();
    }
    if (threadIdx.x == 0) {
        atomicMax((unsigned int*)&ws[362], __float_as_uint(smax[0]));
        atomicMin((unsigned int*)&ws[363], __float_as_uint(smin[0]));
    }
}

__global__ void finalize_kernel(float* __restrict__ out,
                                const uint32_t* __restrict__ ws) {
    #pragma clang fp contract(off)
    int i = blockIdx.x * blockDim.x + threadIdx.x;
    if (i >= NRAY) return;
    float mx = __uint_as_float(ws[362]);
    float mn = __uint_as_float(ws[363]);
    float a = out[(size_t)Bn * 3 * HW + i];
    size_t loff = (size_t)Bn * 4 * HW + i;
    float l = out[loff];
    out[loff] = (a * l) / (mx + mn);
}

extern "C" void kernel_launch(void* const* d_in, const int* in_sizes, int n_in,
                              void* d_out, int out_size, void* d_ws, size_t ws_size,
                              hipStream_t stream) {
    const float* rot   = (const float*)d_in[0];
    const float* cpos  = (const float*)d_in[1];
    const float* focal = (const float*)d_in[2];
    const float* pp    = (const float*)d_in[3];
    const float* pix   = (const float*)d_in[4];
    const float* tpl   = (const float*)d_in[5];
    const float* bg    = (const float*)d_in[6];
    float* out = (float*)d_out;
    uint32_t* ws = (uint32_t*)d_ws;
    float4* aos = (float4*)((char*)d_ws + WS_AOS_BYTE_OFF);

    const bool packed = ws_size >= WS_AOS_BYTE_OFF + WS_AOS_BYTES;

    if (packed) {
        hipLaunchKernelGGL(repack_kernel, dim3((Bn * D3) / 256), dim3(256), 0,
                           stream, tpl, aos, ws);
        hipLaunchKernelGGL(march_kernel<true>, dim3(NRAY / 256), dim3(256), 0,
                           stream, rot, cpos, focal, pp, pix, tpl, aos, bg, out, ws);
    } else {
        hipLaunchKernelGGL(init_keys_kernel, dim3(1), dim3(256), 0, stream, ws);
        hipLaunchKernelGGL(march_kernel<false>, dim3(NRAY / 256), dim3(256), 0,
                           stream, rot, cpos, focal, pp, pix, tpl, aos, bg, out, ws);
    }
    hipLaunchKernelGGL(finalize_kernel, dim3(NRAY / 256), dim3(256), 0, stream,
                       out, ws);
}